// Round 7
// baseline (398.371 us; speedup 1.0000x reference)
//
#include <hip/hip_runtime.h>
#include <stdint.h>

typedef unsigned short u16;
typedef __attribute__((ext_vector_type(8))) short short8;   // 8 x bf16 (4 VGPRs)
typedef __attribute__((ext_vector_type(4))) short bf16x4;   // 4 x bf16 (2 VGPRs)
typedef __attribute__((ext_vector_type(4))) float floatx4;  // MFMA 16x16 C/D
typedef __attribute__((ext_vector_type(2))) int int2v;

#define MFMA32(a, b, c) __builtin_amdgcn_mfma_f32_16x16x32_bf16(a, b, c, 0, 0, 0)
// K=16 bf16 MFMA: device pass has the _1k builtin; host pass only needs to parse.
#if __has_builtin(__builtin_amdgcn_mfma_f32_16x16x16bf16_1k)
#define MFMA16(a, b, c) __builtin_amdgcn_mfma_f32_16x16x16bf16_1k(a, b, c, 0, 0, 0)
#else
#define MFMA16(a, b, c) (c)   // host-pass parse stub; never executed
#endif

__device__ __forceinline__ u16 f2bf(float f) {
  union { float f; unsigned u; } v; v.f = f;
  return (u16)((v.u + 0x7FFFu + ((v.u >> 16) & 1u)) >> 16);  // RNE
}
__device__ __forceinline__ void gl_lds16(const void* g, void* l) {
  __builtin_amdgcn_global_load_lds((const __attribute__((address_space(1))) void*)g,
                                   (__attribute__((address_space(3))) void*)l, 16, 0, 0);
}
__device__ __forceinline__ float exp2_fast(float x) {
#if __has_builtin(__builtin_amdgcn_exp2f)
  return __builtin_amdgcn_exp2f(x);
#else
  return exp2f(x);
#endif
}
// pack two fp32 -> two bf16 (round-half-up) in one u32
__device__ __forceinline__ unsigned pk2bf(float a, float b) {
  unsigned ua = __builtin_bit_cast(unsigned, a);
  unsigned ub = __builtin_bit_cast(unsigned, b);
  return ((ua + 0x8000u) >> 16) | ((ub + 0x8000u) & 0xFFFF0000u);
}

// ---------------- prep: cast x (fp32 -> bf16), 8 elems/thread ----------------
__global__ __launch_bounds__(256) void k_cast_x(const float* __restrict__ x, u16* __restrict__ xb) {
  int t = blockIdx.x * 256 + threadIdx.x;
  const float4* xv = (const float4*)x;
  float4 a = xv[2 * t], b = xv[2 * t + 1];
  short8 o;
  o[0] = f2bf(a.x); o[1] = f2bf(a.y); o[2] = f2bf(a.z); o[3] = f2bf(a.w);
  o[4] = f2bf(b.x); o[5] = f2bf(b.y); o[6] = f2bf(b.z); o[7] = f2bf(b.w);
  ((short8*)xb)[t] = o;
}

// ------------- prep: transpose+cast w_qkv [512,1536] and w_out [512,512] -----
__global__ __launch_bounds__(256) void k_prep_w(const float* __restrict__ wqkv, const float* __restrict__ wout,
                                                u16* __restrict__ wqkvT, u16* __restrict__ woutT) {
  int t = blockIdx.x * 256 + threadIdx.x;
  if (t < 786432) {
    int n = t >> 9, k = t & 511;
    wqkvT[t] = f2bf(wqkv[k * 1536 + n]);
  } else {
    int u = t - 786432;
    int n = u >> 9, k = u & 511;
    woutT[u] = f2bf(wout[k * 512 + n]);
  }
}

// ---- prep: bias in TRANSPOSED attn lane order, value = (b-8)*log2e bf16 -----
// layout (u16): [h][qt][kt][w][kvt(8)][qi(2)][lane(64)][r(4)]; value at
// (kv = kt*128+kvt*16+(lane>>4)*4+r, q = qt*128+w*32+qi*16+(lane&15)).
__global__ __launch_bounds__(256) void k_prep_bias(const int* __restrict__ rel, const float* __restrict__ tab,
                                                   u16* __restrict__ biasb) {
  int t = blockIdx.x * 256 + threadIdx.x;   // 2,097,152 threads, 4 values each
  int lane = t & 63;
  int qi   = (t >> 6) & 1;
  int kvt  = (t >> 7) & 7;
  int w    = (t >> 10) & 3;
  int kt   = (t >> 12) & 7;
  int qt   = (t >> 15) & 7;
  int h    = t >> 18;
  int q  = qt * 128 + w * 32 + qi * 16 + (lane & 15);
  int kv = kt * 128 + kvt * 16 + (lane >> 4) * 4;
  const int* rr = rel + q * 1024 + kv;
  bf16x4 o;
  #pragma unroll
  for (int r = 0; r < 4; r++) {
    int idx = rr[r];
    o[r] = (short)f2bf((tab[idx * 8 + h] - 8.0f) * 1.44269504f);
  }
  ((bf16x4*)biasb)[t] = o;
}

// ---------------- GEMM1: qkv = xb @ wqkvT^T -> Q,K [b,h,n,d], V^T [b,h,d,n] --
// V^T columns are stored PERMUTED within each 128-col tile: element kv
// (= kb*32 + u*16 + qd*4 + j) lands at pos = kb*32 + qd*8 + u*4 + j, so that
// one 16B chunk holds the two K=16 A-fragments the attn PV loop needs.
__global__ __launch_bounds__(256) void k_gemm_qkv(const u16* __restrict__ xb, const u16* __restrict__ wT,
                                                  u16* __restrict__ qbuf, u16* __restrict__ kbuf,
                                                  u16* __restrict__ vtbuf) {
  __shared__ u16 sm[17408];
  const int bn = blockIdx.x, bm = blockIdx.y;
  const int tid = threadIdx.x, w = tid >> 6, lane = tid & 63;
  const int quad = lane >> 4, l15 = lane & 15;
  const int wr = w >> 1, wc = w & 1;
  const u16* Ag = xb + (size_t)bm * 128 * 512;
  const u16* Bg = wT + (size_t)bn * 128 * 512;
  floatx4 acc[4][4];
  floatx4 zero = {0.f, 0.f, 0.f, 0.f};
  #pragma unroll
  for (int i = 0; i < 4; i++)
    #pragma unroll
    for (int j = 0; j < 4; j++) acc[i][j] = zero;

  for (int kb = 0; kb < 512; kb += 32) {
    __syncthreads();
    #pragma unroll
    for (int i = 0; i < 2; i++) {
      int c = w * 128 + i * 64 + lane;
      int row = c >> 2, col = (c & 3) * 8;
      gl_lds16(Ag + (size_t)row * 512 + kb + col, &sm[(w * 128 + i * 64) * 8]);
      gl_lds16(Bg + (size_t)row * 512 + kb + col, &sm[4096 + (w * 128 + i * 64) * 8]);
    }
    __syncthreads();
    short8 af[4], bf[4];
    #pragma unroll
    for (int ti = 0; ti < 4; ti++)
      af[ti] = *(const short8*)&sm[(wr * 64 + ti * 16 + l15) * 32 + quad * 8];
    #pragma unroll
    for (int tj = 0; tj < 4; tj++)
      bf[tj] = *(const short8*)&sm[4096 + (wc * 64 + tj * 16 + l15) * 32 + quad * 8];
    #pragma unroll
    for (int ti = 0; ti < 4; ti++)
      #pragma unroll
      for (int tj = 0; tj < 4; tj++)
        acc[ti][tj] = MFMA32(af[ti], bf[tj], acc[ti][tj]);
  }
  __syncthreads();
  #pragma unroll
  for (int ti = 0; ti < 4; ti++)
    #pragma unroll
    for (int tj = 0; tj < 4; tj++)
      #pragma unroll
      for (int r = 0; r < 4; r++)
        sm[(wr * 64 + ti * 16 + quad * 4 + r) * 136 + wc * 64 + tj * 16 + l15] = f2bf(acc[ti][tj][r]);
  __syncthreads();
  const int b = bm >> 3;
  const int nrow0 = (bm & 7) * 128;
  if (bn < 8) {
    u16* dst = (bn < 4) ? qbuf : kbuf;
    #pragma unroll
    for (int i = 0; i < 8; i++) {
      int chunk = i * 256 + tid;
      int r = chunk >> 4, c8 = chunk & 15;
      int nin = (bn & 3) * 128 + c8 * 8;
      int h = nin >> 6, d = nin & 63;
      uint4 val = *(const uint4*)&sm[r * 136 + c8 * 8];
      *(uint4*)&dst[(((size_t)(b * 8 + h)) * 1024 + nrow0 + r) * 64 + d] = val;
    }
  } else {
    #pragma unroll
    for (int i = 0; i < 8; i++) {
      int chunk = i * 256 + tid;
      int dcol = chunk & 127, nr8 = chunk >> 7;
      int nin = (bn & 3) * 128 + dcol;
      int h = nin >> 6, d = nin & 63;
      short8 v;
      #pragma unroll
      for (int j = 0; j < 8; j++) v[j] = (short)sm[(nr8 * 8 + j) * 136 + dcol];
      int n0 = nr8 * 8;
      int kb = n0 >> 5, u = (n0 >> 4) & 1, qd0 = (n0 >> 2) & 3;
      int pos0 = kb * 32 + qd0 * 8 + u * 4;
      u16* dst = &vtbuf[(((size_t)(b * 8 + h)) * 64 + d) * 1024 + nrow0 + pos0];
      *(bf16x4*)&dst[0] = __builtin_shufflevector(v, v, 0, 1, 2, 3);
      *(bf16x4*)&dst[8] = __builtin_shufflevector(v, v, 4, 5, 6, 7);
    }
  }
}

// ---------------- flash attention v5: transposed-S, register-resident P ------
// S^T = K.Q^T (operand swap, same frag loads).  C-layout of S^T (kv=quad*4+r,
// q=l15) IS the B-frag layout of mfma_f32_16x16x16_bf16, so P^T feeds
// O^T = V^T.P^T straight from registers: no P LDS, no cross-lane moves.
// LDS = K/V double-buffer only (64 KB).  One barrier per kt, prefetch-ahead.
__global__ __launch_bounds__(256, 2) void k_attn(const u16* __restrict__ qbuf, const u16* __restrict__ kbuf,
                                                 const u16* __restrict__ vtbuf, const u16* __restrict__ biasb,
                                                 u16* __restrict__ attn_out) {
  __shared__ u16 sm[32768];   // K0 [0,8K) V0 [8K,16K) K1 [16K,24K) V1 [24K,32K)
  const int b = blockIdx.x, h = blockIdx.y >> 3, qt = blockIdx.y & 7;
  const int tid = threadIdx.x, w = tid >> 6, lane = tid & 63;
  const int quad = lane >> 4, l15 = lane & 15;
  const int xm = l15 & 7;
  const size_t bh = (size_t)(b * 8 + h);
  const u16* qg = qbuf + (bh * 1024 + (size_t)qt * 128) * 64;
  const u16* kg = kbuf + bh * 1024 * 64;
  const u16* vg = vtbuf + bh * 64 * 1024;
  const u16* bg = biasb + (size_t)h * 1048576 + (size_t)qt * 131072 + (size_t)w * 4096 + lane * 4;

  // staging source indices (swizzled), loop-invariant
  int rK[4], cK[4], dV[4], cV[4];
  #pragma unroll
  for (int i = 0; i < 4; i++) {
    int p = (w * 4 + i) * 64 + lane;
    rK[i] = p >> 3;  cK[i] = (p & 7) ^ (rK[i] & 7);
    dV[i] = p >> 4;  cV[i] = (p & 15) ^ (dV[i] & 7);
  }

  // Q fragments: direct global 16B loads (once per block); B-operand layout
  short8 qf[2][2];
  #pragma unroll
  for (int qi = 0; qi < 2; qi++)
    #pragma unroll
    for (int kk = 0; kk < 2; kk++)
      qf[qi][kk] = *(const short8*)&qg[(w * 32 + qi * 16 + l15) * 64 + kk * 32 + quad * 8];

  floatx4 oacc[4][2];   // O^T: [dj][qi], row d=dj*16+quad*4+r, col q=qi*16+l15
  floatx4 zero = {0.f, 0.f, 0.f, 0.f};
  #pragma unroll
  for (int dj = 0; dj < 4; dj++)
    #pragma unroll
    for (int qi = 0; qi < 2; qi++) oacc[dj][qi] = zero;
  float lrow[2] = {0.f, 0.f};

  const float SC = 0.125f * 1.44269504f;

  // preload tile 0 into buffer 0
  #pragma unroll
  for (int i = 0; i < 4; i++) {
    gl_lds16(kg + (size_t)rK[i] * 64 + cK[i] * 8, &sm[(w * 4 + i) * 512]);
    gl_lds16(vg + (size_t)dV[i] * 1024 + cV[i] * 8, &sm[8192 + (w * 4 + i) * 512]);
  }
  __syncthreads();

  for (int kt = 0; kt < 8; kt++) {
    const int cur = (kt & 1) ? 16384 : 0;
    const int nxt = (kt & 1) ? 0 : 16384;
    if (kt < 7) {
      #pragma unroll
      for (int i = 0; i < 4; i++) {
        gl_lds16(kg + (size_t)((kt + 1) * 128 + rK[i]) * 64 + cK[i] * 8, &sm[nxt + (w * 4 + i) * 512]);
        gl_lds16(vg + (size_t)dV[i] * 1024 + (kt + 1) * 128 + cV[i] * 8, &sm[nxt + 8192 + (w * 4 + i) * 512]);
      }
    }
    const u16* bkt = bg + kt * 16384;

    #pragma unroll
    for (int tjh = 0; tjh < 2; tjh++) {
      // bias for this half: uint2 per (kvt,qi), transposed layout
      uint2 bu[4][2];
      #pragma unroll
      for (int kl = 0; kl < 4; kl++)
        #pragma unroll
        for (int qi = 0; qi < 2; qi++)
          bu[kl][qi] = *(const uint2*)&bkt[((tjh * 4 + kl) * 2 + qi) * 256];
      // S^T = K.Q^T for 64 kv rows
      floatx4 sacc[4][2];
      #pragma unroll
      for (int kl = 0; kl < 4; kl++) { sacc[kl][0] = zero; sacc[kl][1] = zero; }
      #pragma unroll
      for (int kl = 0; kl < 4; kl++) {
        int kvt = tjh * 4 + kl;
        #pragma unroll
        for (int kk = 0; kk < 2; kk++) {
          short8 kf = *(const short8*)&sm[cur + (kvt * 16 + l15) * 64 + ((kk * 4 + quad) ^ xm) * 8];
          sacc[kl][0] = MFMA32(kf, qf[0][kk], sacc[kl][0]);
          sacc[kl][1] = MFMA32(kf, qf[1][kk], sacc[kl][1]);
        }
      }
      // softmax (no max-subtract; bias pre-shifted by -8, log2e folded),
      // pack P^T straight into mfma16 B-fragments (register-resident)
      bf16x4 pk[4][2];
      #pragma unroll
      for (int kl = 0; kl < 4; kl++)
        #pragma unroll
        for (int qi = 0; qi < 2; qi++) {
          unsigned blo = bu[kl][qi].x, bhi = bu[kl][qi].y;
          float b0 = __builtin_bit_cast(float, blo << 16);
          float b1 = __builtin_bit_cast(float, blo & 0xFFFF0000u);
          float b2 = __builtin_bit_cast(float, bhi << 16);
          float b3 = __builtin_bit_cast(float, bhi & 0xFFFF0000u);
          float p0 = exp2_fast(sacc[kl][qi][0] * SC + b0);
          float p1 = exp2_fast(sacc[kl][qi][1] * SC + b1);
          float p2 = exp2_fast(sacc[kl][qi][2] * SC + b2);
          float p3 = exp2_fast(sacc[kl][qi][3] * SC + b3);
          lrow[qi] += (p0 + p1) + (p2 + p3);
          int2v pp = {(int)pk2bf(p0, p1), (int)pk2bf(p2, p3)};
          pk[kl][qi] = __builtin_bit_cast(bf16x4, pp);
        }
      // O^T += V^T.P^T  (V: one b128 = two K=16 A-frags, pre-permuted cols)
      #pragma unroll
      for (int kbl = 0; kbl < 2; kbl++) {
        int kb = tjh * 2 + kbl;
        #pragma unroll
        for (int dj = 0; dj < 4; dj++) {
          short8 vv = *(const short8*)&sm[cur + 8192 + (dj * 16 + l15) * 128 + ((kb * 4 + quad) ^ xm) * 8];
          bf16x4 vlo = __builtin_shufflevector(vv, vv, 0, 1, 2, 3);
          bf16x4 vhi = __builtin_shufflevector(vv, vv, 4, 5, 6, 7);
          #pragma unroll
          for (int qi = 0; qi < 2; qi++) {
            oacc[dj][qi] = MFMA16(vlo, pk[kbl * 2 + 0][qi], oacc[dj][qi]);
            oacc[dj][qi] = MFMA16(vhi, pk[kbl * 2 + 1][qi], oacc[dj][qi]);
          }
        }
      }
    }
    __syncthreads();  // buffer handoff; vmcnt(0) drains an aged prefetch
  }

  // epilogue: reduce row sums across quads, normalize, 8B packed stores
  #pragma unroll
  for (int qi = 0; qi < 2; qi++) {
    float s = lrow[qi];
    s += __shfl_xor(s, 16);
    s += __shfl_xor(s, 32);
    float inv = 1.f / s;
    int n = b * 1024 + qt * 128 + w * 32 + qi * 16 + l15;
    #pragma unroll
    for (int dj = 0; dj < 4; dj++) {
      unsigned lo = ((unsigned)f2bf(oacc[dj][qi][0] * inv)) | ((unsigned)f2bf(oacc[dj][qi][1] * inv) << 16);
      unsigned hi = ((unsigned)f2bf(oacc[dj][qi][2] * inv)) | ((unsigned)f2bf(oacc[dj][qi][3] * inv) << 16);
      int2v o = {(int)lo, (int)hi};
      *(int2v*)&attn_out[(size_t)n * 512 + h * 64 + dj * 16 + quad * 4] = o;
    }
  }
}

// ---------------- GEMM3: out = attn @ w_out + b_out (fp32 out) ---------------
__global__ __launch_bounds__(256) void k_gemm_out(const u16* __restrict__ ab, const u16* __restrict__ wT,
                                                  const float* __restrict__ bout, float* __restrict__ out) {
  __shared__ u16 sm[8192];
  const int bn = blockIdx.x, bm = blockIdx.y;
  const int tid = threadIdx.x, w = tid >> 6, lane = tid & 63;
  const int quad = lane >> 4, l15 = lane & 15;
  const int wr = w >> 1, wc = w & 1;
  const u16* Ag = ab + (size_t)bm * 128 * 512;
  const u16* Bg = wT + (size_t)bn * 128 * 512;
  float bv[4];
  #pragma unroll
  for (int tj = 0; tj < 4; tj++) bv[tj] = bout[bn * 128 + wc * 64 + tj * 16 + l15];
  floatx4 acc[4][4];
  floatx4 zero = {0.f, 0.f, 0.f, 0.f};
  #pragma unroll
  for (int i = 0; i < 4; i++)
    #pragma unroll
    for (int j = 0; j < 4; j++) acc[i][j] = zero;

  for (int kb = 0; kb < 512; kb += 32) {
    __syncthreads();
    #pragma unroll
    for (int i = 0; i < 2; i++) {
      int c = w * 128 + i * 64 + lane;
      int row = c >> 2, col = (c & 3) * 8;
      gl_lds16(Ag + (size_t)row * 512 + kb + col, &sm[(w * 128 + i * 64) * 8]);
      gl_lds16(Bg + (size_t)row * 512 + kb + col, &sm[4096 + (w * 128 + i * 64) * 8]);
    }
    __syncthreads();
    short8 af[4], bf[4];
    #pragma unroll
    for (int ti = 0; ti < 4; ti++)
      af[ti] = *(const short8*)&sm[(wr * 64 + ti * 16 + l15) * 32 + quad * 8];
    #pragma unroll
    for (int tj = 0; tj < 4; tj++)
      bf[tj] = *(const short8*)&sm[4096 + (wc * 64 + tj * 16 + l15) * 32 + quad * 8];
    #pragma unroll
    for (int ti = 0; ti < 4; ti++)
      #pragma unroll
      for (int tj = 0; tj < 4; tj++)
        acc[ti][tj] = MFMA32(af[ti], bf[tj], acc[ti][tj]);
  }
  #pragma unroll
  for (int ti = 0; ti < 4; ti++)
    #pragma unroll
    for (int tj = 0; tj < 4; tj++)
      #pragma unroll
      for (int r = 0; r < 4; r++) {
        int row = bm * 128 + wr * 64 + ti * 16 + quad * 4 + r;
        int colg = bn * 128 + wc * 64 + tj * 16 + l15;
        out[(size_t)row * 512 + colg] = acc[ti][tj][r] + bv[tj];
      }
}

// ---------------- launch -----------------------------------------------------
extern "C" void kernel_launch(void* const* d_in, const int* in_sizes, int n_in,
                              void* d_out, int out_size, void* d_ws, size_t ws_size,
                              hipStream_t stream) {
  const float* x    = (const float*)d_in[0];
  const float* wqkv = (const float*)d_in[1];
  const float* wout = (const float*)d_in[2];
  const float* bout = (const float*)d_in[3];
  const float* btab = (const float*)d_in[4];
  const int*   rel  = (const int*)d_in[5];
  char* ws = (char*)d_ws;
  u16* xb    = (u16*)(ws + 0);           // x bf16, reused as attn_out
  u16* qbuf  = (u16*)(ws + 33554432);
  u16* kbuf  = (u16*)(ws + 67108864);
  u16* vtbuf = (u16*)(ws + 100663296);   // V^T [b,h,d,n], cols permuted per 128
  u16* biasb = (u16*)(ws + 134217728);   // transposed-swizzled bias
  u16* wqkvT = (u16*)(ws + 150994944);
  u16* woutT = (u16*)(ws + 152567808);
  float* out = (float*)d_out;

  k_cast_x  <<<8192, 256, 0, stream>>>(x, xb);
  k_prep_w  <<<4096, 256, 0, stream>>>(wqkv, wout, wqkvT, woutT);
  k_prep_bias<<<8192, 256, 0, stream>>>(rel, btab, biasb);
  k_gemm_qkv<<<dim3(12, 256), 256, 0, stream>>>(xb, wqkvT, qbuf, kbuf, vtbuf);
  k_attn    <<<dim3(32, 64), 256, 0, stream>>>(qbuf, kbuf, vtbuf, biasb, xb);
  k_gemm_out<<<dim3(4, 256), 256, 0, stream>>>(xb, woutT, bout, out);
}